// Round 9
// baseline (12647.031 us; speedup 1.0000x reference)
//
#include <hip/hip_runtime.h>

// BI-LSTM (TF LSTMCell w/ projection), T=160 B=640 F=40 HID=768 PROJ=256, 3 layers x 2 dirs.
// R9: DATAFLOW PERSISTENT KERNEL. R8's counters proved per-step compute is ~5us and the rest
// is launch/fence overhead; its regression came from consumer __threadfence = buffer_inv (L2
// wipe) during weight streaming. This design has ZERO fences:
//  - cross-block data (h rings, g) via __hip_atomic_{load,store}(RELAXED, AGENT): per-
//    instruction LLC coherence, L2 weight cache never invalidated.
//  - strip-local completion counters (plain device-scope atomicAdd after __syncthreads;
//    relaxed-load polling with s_sleep) -- no grid barrier, self-timed wavefront.
//  - 780 blocks = 780 tiles (720 gate + 60 proj), each loops s=0..161; cooperative launch +
//    __launch_bounds__(512,8) (forces <=64 VGPR -> 4 blocks/CU = 1024 slots) guarantees
//    co-residency; spin watchdog converts any protocol bug into a loud failure, not a hang.
//  - h-ring deepened to 8 slots; one WAR wait (proj vs next-layer reader at s-7), DAG-safe.

typedef _Float16 h8 __attribute__((ext_vector_type(8)));
typedef float f4 __attribute__((ext_vector_type(4)));

#define T_STEPS 160
#define NB 640
#define HID 768
#define PROJ 256
#define NGATE 3072
#define SLOT ((size_t)NB * PROJ)   // halves per h time-slot

__device__ __forceinline__ float sigm(float x) { return 1.0f / (1.0f + __expf(-x)); }
__device__ __forceinline__ float tanh_fast(float x) { return 2.0f / (1.0f + __expf(-2.0f * x)) - 1.0f; }

// ---- agent-scope (cross-XCD coherent) data movement, no cache invalidates ----
__device__ __forceinline__ h8 aload16(const _Float16* p) {
  const unsigned long long* q = (const unsigned long long*)p;
  unsigned long long lo = __hip_atomic_load(q,     __ATOMIC_RELAXED, __HIP_MEMORY_SCOPE_AGENT);
  unsigned long long hi = __hip_atomic_load(q + 1, __ATOMIC_RELAXED, __HIP_MEMORY_SCOPE_AGENT);
  union { unsigned long long u[2]; h8 v; } x; x.u[0] = lo; x.u[1] = hi; return x.v;
}
__device__ __forceinline__ void astore8(_Float16* p, unsigned long long v) {
  __hip_atomic_store((unsigned long long*)p, v, __ATOMIC_RELAXED, __HIP_MEMORY_SCOPE_AGENT);
}
__device__ __forceinline__ void astore4(_Float16* p, unsigned v) {
  __hip_atomic_store((unsigned*)p, v, __ATOMIC_RELAXED, __HIP_MEMORY_SCOPE_AGENT);
}
__device__ __forceinline__ unsigned pack2h(float a, float b) {
  union { _Float16 h[2]; unsigned u; } x;
  x.h[0] = (_Float16)a; x.h[1] = (_Float16)b; return x.u;
}

struct DFArgs {
  const _Float16* X16;
  const _Float16* WkT[6];   // gate-interleaved [3072][Kpad]
  const float*    bias[6];
  const _Float16* WpT[6];   // [256][768]
  _Float16* Hbuf;           // [6][8 slots][640*256]
  float*    cst;            // [6][640*768]
  _Float16* gbuf;           // [6][640*768]
  _Float16* embed;          // [d][which][640*256]
  int* cntG;                // [162][6][5]
  int* cntP;                // [162][6][5]
};

__device__ __forceinline__ int cidx(int s, int z, int by) { return (s * 6 + z) * 5 + by; }

__device__ __forceinline__ void wait_ge(int* p, int tgt) {
  if (threadIdx.x == 0) {
    int it = 0;
    while (__hip_atomic_load(p, __ATOMIC_RELAXED, __HIP_MEMORY_SCOPE_AGENT) < tgt) {
      __builtin_amdgcn_s_sleep(8);
      if (++it > (1 << 22)) break;   // watchdog: fail loud, never hang
    }
  }
  __syncthreads();
}

__global__ __launch_bounds__(512, 8) void lstm_df(DFArgs a) {
  __shared__ __align__(16) char sm[36864];       // As 18KB | Bs 18KB; overlays: zs / hs
  _Float16 (*As)[72] = (_Float16(*)[72])sm;      // [128][72]
  _Float16 (*Bs)[72] = (_Float16(*)[72])(sm + 18432);
  float (*zs)[65] = (float(*)[65])sm;            // [128][65] f32 (gate epilogue)
  _Float16* hs = (_Float16*)sm;                  // [128][128] fp16 (proj epilogue)

  const int tid = threadIdx.x;
  const int lane = tid & 63;
  const int wv = tid >> 6;         // 0..7
  const int lr = tid >> 3;         // 0..63
  const int lkg = (tid & 7) * 8;   // 0,8,..,56
  const int b = blockIdx.x;

  if (b < 720) {
    // ==================== gate block: fixed tile (z, by, n) ====================
    const int z = b / 120;
    const int rem = b - z * 120;
    const int n0 = (rem % 24) * 128;
    const int by = rem / 24;
    const int m0 = by * 128;
    const int l = z >> 1, d = z & 1;
    const int w0 = (l == 0) ? 64 : 256;
    const int K  = (l == 0) ? 320 : 512;
    const _Float16* Bw = a.WkT[z];
    const float* bias = a.bias[z];
    float* cstate = a.cst + (size_t)z * NB * HID;
    _Float16* gout = a.gbuf + (size_t)z * NB * HID;
    const int wm = (wv & 3) * 32;
    const int wn = (wv >> 2) * 64;

    for (int s = 0; s <= 161; ++s) {
      const int t = s - l;
      if (t < 0 || t > 159) continue;
      const int tt = d ? 159 - t : t;

      // dependencies: own-layer h(t-1 or t+1) and prev-layer h(t), this strip only
      if (t > 0) wait_ge(a.cntP + cidx(s - 1, z, by), 2);
      if (l > 0) wait_ge(a.cntP + cidx(s - 1, z - 2, by), 2);

      const _Float16* A0 = (l == 0)
          ? a.X16 + (size_t)tt * NB * 64
          : a.Hbuf + ((size_t)(z - 2) * 8 + ((tt + 1) & 7)) * SLOT;
      const _Float16* A1 = a.Hbuf + ((size_t)z * 8 + (d == 0 ? (tt & 7) : ((tt + 2) & 7))) * SLOT;

      f4 acc[2][4] = {};
      for (int k0 = 0; k0 < K; k0 += 64) {
        const int gk = k0 + lkg;
        h8 av0, av1;
        if (gk < w0) {
          if (l == 0) {   // X16: static, normal cached loads
            av0 = *(const h8*)(A0 + (size_t)(m0 + lr) * 64 + gk);
            av1 = *(const h8*)(A0 + (size_t)(m0 + lr + 64) * 64 + gk);
          } else {        // prev-layer h ring: agent-coherent loads
            av0 = aload16(A0 + (size_t)(m0 + lr) * 256 + gk);
            av1 = aload16(A0 + (size_t)(m0 + lr + 64) * 256 + gk);
          }
        } else {          // own h ring: agent-coherent loads
          av0 = aload16(A1 + (size_t)(m0 + lr) * 256 + (gk - w0));
          av1 = aload16(A1 + (size_t)(m0 + lr + 64) * 256 + (gk - w0));
        }
        h8 bv0 = *(const h8*)(Bw + (size_t)(n0 + lr) * K + gk);
        h8 bv1 = *(const h8*)(Bw + (size_t)(n0 + lr + 64) * K + gk);
        __syncthreads();
        *(h8*)&As[lr][lkg] = av0;
        *(h8*)&As[lr + 64][lkg] = av1;
        *(h8*)&Bs[lr][lkg] = bv0;
        *(h8*)&Bs[lr + 64][lkg] = bv1;
        __syncthreads();
#pragma unroll
        for (int kk = 0; kk < 2; ++kk) {
          const int kq = ((lane >> 4) * 8) + kk * 32;
          h8 af[2], bf[4];
#pragma unroll
          for (int i = 0; i < 2; ++i)
            af[i] = *(const h8*)&As[wm + (lane & 15) + 16 * i][kq];
#pragma unroll
          for (int j = 0; j < 4; ++j)
            bf[j] = *(const h8*)&Bs[wn + (lane & 15) + 16 * j][kq];
#pragma unroll
          for (int i = 0; i < 2; ++i)
#pragma unroll
            for (int j = 0; j < 4; ++j)
              acc[i][j] = __builtin_amdgcn_mfma_f32_16x16x32_f16(af[i], bf[j], acc[i][j], 0, 0, 0);
        }
      }

      // epilogue: two 64-col passes; g written as packed u32 agent stores
#pragma unroll
      for (int p2 = 0; p2 < 2; ++p2) {
        __syncthreads();
        if ((wv >> 2) == p2) {
#pragma unroll
          for (int mi = 0; mi < 2; ++mi)
#pragma unroll
            for (int ni = 0; ni < 4; ++ni)
#pragma unroll
              for (int r = 0; r < 4; ++r) {
                int row = wm + mi * 16 + ((lane >> 4) << 2) + r;
                int col = ni * 16 + (lane & 15);
                zs[row][col] = acc[mi][ni][r];
              }
        }
        __syncthreads();
        const int u0 = (n0 + p2 * 64) >> 2;
#pragma unroll
        for (int it = 0; it < 2; ++it) {
          int item = it * 512 + tid;    // 128 rows x 8 unit-pairs
          int row = item >> 3;
          int up = item & 7;
          int ua = 2 * up, ub = 2 * up + 1;
          float g2[2];
#pragma unroll
          for (int q = 0; q < 2; ++q) {
            int u = (q == 0) ? ua : ub;
            float zi = zs[row][4 * u + 0] + bias[0 * HID + u0 + u];
            float zj = zs[row][4 * u + 1] + bias[1 * HID + u0 + u];
            float zf = zs[row][4 * u + 2] + bias[2 * HID + u0 + u];
            float zo = zs[row][4 * u + 3] + bias[3 * HID + u0 + u];
            size_t co = (size_t)(m0 + row) * HID + u0 + u;
            float cold = cstate[co];
            float cnew = sigm(zf + 1.0f) * cold + sigm(zi) * tanh_fast(zj);
            cstate[co] = cnew;
            g2[q] = sigm(zo) * tanh_fast(cnew);
          }
          astore4(gout + (size_t)(m0 + row) * HID + u0 + ua, pack2h(g2[0], g2[1]));
        }
      }

      __syncthreads();                 // all waves' g stores acked (vmcnt(0) at barrier)
      if (tid == 0) atomicAdd(a.cntG + cidx(s, z, by), 1);
    }
  } else {
    // ==================== proj block: fixed tile (z, by, n-half) ====================
    const int p = b - 720;
    const int z = p / 10;
    const int rem = p - z * 10;
    const int nh = rem & 1;
    const int by = rem >> 1;
    const int m0 = by * 128;
    const int nb0 = nh * 128;
    const int l = z >> 1, d = z & 1;
    const _Float16* G = a.gbuf + (size_t)z * NB * HID;
    const _Float16* B = a.WpT[z];
    const int wm = (wv & 3) * 32;
    const int wn = (wv >> 2) * 64;

    for (int s = 0; s <= 161; ++s) {
      const int t = s - l;
      if (t < 0 || t > 159) continue;
      const int tt = d ? 159 - t : t;

      wait_ge(a.cntG + cidx(s, z, by), 24);
      if (l < 2) {                     // WAR: next-layer reader of the slot we overwrite
        int sr = s - 7;
        int trr = sr - (l + 1);
        if (trr >= 0 && trr <= 159) wait_ge(a.cntG + cidx(sr, z + 2, by), 24);
      }

      _Float16* outp = a.Hbuf + ((size_t)z * 8 + ((tt + 1) & 7)) * SLOT;
      _Float16* out2 = nullptr;
      if (l == 2 && (tt == 0 || tt == 159))
        out2 = a.embed + ((size_t)d * 2 + (tt == 0 ? 0 : 1)) * SLOT;

      f4 acc[2][4] = {};
      for (int k0 = 0; k0 < HID; k0 += 64) {
        const int gk = k0 + lkg;
        h8 av0 = aload16(G + (size_t)(m0 + lr) * HID + gk);
        h8 av1 = aload16(G + (size_t)(m0 + lr + 64) * HID + gk);
        h8 bv0 = *(const h8*)(B + (size_t)(nb0 + lr) * HID + gk);
        h8 bv1 = *(const h8*)(B + (size_t)(nb0 + lr + 64) * HID + gk);
        __syncthreads();
        *(h8*)&As[lr][lkg] = av0;
        *(h8*)&As[lr + 64][lkg] = av1;
        *(h8*)&Bs[lr][lkg] = bv0;
        *(h8*)&Bs[lr + 64][lkg] = bv1;
        __syncthreads();
#pragma unroll
        for (int kk = 0; kk < 2; ++kk) {
          const int kq = ((lane >> 4) * 8) + kk * 32;
          h8 af[2], bf[4];
#pragma unroll
          for (int i = 0; i < 2; ++i)
            af[i] = *(const h8*)&As[wm + (lane & 15) + 16 * i][kq];
#pragma unroll
          for (int j = 0; j < 4; ++j)
            bf[j] = *(const h8*)&Bs[wn + (lane & 15) + 16 * j][kq];
#pragma unroll
          for (int i = 0; i < 2; ++i)
#pragma unroll
            for (int j = 0; j < 4; ++j)
              acc[i][j] = __builtin_amdgcn_mfma_f32_16x16x32_f16(af[i], bf[j], acc[i][j], 0, 0, 0);
        }
      }

      // stage 128x128 result in LDS, then packed u64 agent stores
      __syncthreads();
#pragma unroll
      for (int mi = 0; mi < 2; ++mi)
#pragma unroll
        for (int ni = 0; ni < 4; ++ni)
#pragma unroll
          for (int r = 0; r < 4; ++r) {
            int row = wm + mi * 16 + ((lane >> 4) << 2) + r;
            int col = wn + ni * 16 + (lane & 15);
            hs[row * 128 + col] = (_Float16)acc[mi][ni][r];
          }
      __syncthreads();
#pragma unroll
      for (int it = 0; it < 8; ++it) {
        int idx = it * 512 + tid;      // 4096 u64: 128 rows x 32 col-groups
        int row = idx >> 5;
        int c8 = idx & 31;
        unsigned long long v = *(const unsigned long long*)&hs[row * 128 + c8 * 4];
        size_t o = (size_t)(m0 + row) * PROJ + nb0 + c8 * 4;
        astore8(outp + o, v);
        if (out2) *(unsigned long long*)(out2 + o) = v;
      }

      __syncthreads();
      if (tid == 0) atomicAdd(a.cntP + cidx(s, z, by), 1);
    }
  }
}

// ---------------- prep kernels (unchanged) ----------------
__global__ void convX(const float* __restrict__ X, _Float16* __restrict__ X16, size_t total) {
  size_t i = (size_t)blockIdx.x * 256 + threadIdx.x;
  if (i >= total) return;
  int p = (int)(i & 63);
  size_t tb = i >> 6;
  float v = (p < 40) ? X[tb * 40 + p] : 0.0f;
  X16[i] = (_Float16)v;
}

__global__ void conv_wk(const float* __restrict__ Wk, _Float16* __restrict__ out,
                        int mode, int Kpad, size_t total) {
  size_t i = (size_t)blockIdx.x * 256 + threadIdx.x;
  if (i >= total) return;
  int k = (int)(i % Kpad);
  int n = (int)(i / Kpad);
  int u = n >> 2, g = n & 3;
  int col = g * HID + u;
  float v;
  if (mode == 0) {
    if (k < 40)      v = Wk[(size_t)k * NGATE + col];
    else if (k < 64) v = 0.0f;
    else             v = Wk[(size_t)(k - 24) * NGATE + col];
  } else {
    v = Wk[(size_t)k * NGATE + col];
  }
  out[i] = (_Float16)v;
}

__global__ void conv_wp(const float* __restrict__ Wp, _Float16* __restrict__ out, size_t total) {
  size_t i = (size_t)blockIdx.x * 256 + threadIdx.x;
  if (i >= total) return;
  int k = (int)(i % HID);
  int c = (int)(i / HID);
  out[i] = (_Float16)Wp[(size_t)k * PROJ + c];
}

// ---------------- readout (unchanged) ----------------
__global__ __launch_bounds__(256) void readout(const _Float16* __restrict__ E, float* __restrict__ out) {
  int b = blockIdx.x, tid = threadIdx.x;
  float v[2];
  float ss = 0.0f;
#pragma unroll
  for (int i = 0; i < 2; ++i) {
    int j = tid + i * 256;
    int d = j >> 8, c = j & 255;
    const _Float16* base = E + (size_t)d * 2 * SLOT;
    float av = (float)base[(size_t)b * PROJ + c];
    float zv = (float)base[SLOT + (size_t)b * PROJ + c];
    v[i] = 0.5f * (av + zv);
    ss += v[i] * v[i];
  }
#pragma unroll
  for (int off = 32; off; off >>= 1) ss += __shfl_down(ss, off);
  __shared__ float ps[4];
  if ((tid & 63) == 0) ps[tid >> 6] = ss;
  __syncthreads();
  float tot = ps[0] + ps[1] + ps[2] + ps[3];
  float nrm = rsqrtf(fmaxf(tot, 1e-12f));
  out[(size_t)b * 512 + tid] = v[0] * nrm;
  out[(size_t)b * 512 + tid + 256] = v[1] * nrm;
}

extern "C" void kernel_launch(void* const* d_in, const int* in_sizes, int n_in,
                              void* d_out, int out_size, void* d_ws, size_t ws_size,
                              hipStream_t stream) {
  (void)in_sizes; (void)n_in; (void)out_size; (void)ws_size;
  const float* X = (const float*)d_in[0];
  const float* Wk[2][3]; const float* Bi[2][3]; const float* Wp[2][3];
  for (int d = 0; d < 2; ++d)
    for (int l = 0; l < 3; ++l) {
      int base = 1 + d * 9 + l * 3;
      Wk[d][l] = (const float*)d_in[base];
      Bi[d][l] = (const float*)d_in[base + 1];
      Wp[d][l] = (const float*)d_in[base + 2];
    }

  char* ws = (char*)d_ws;
  size_t off = 0;
  auto alloc = [&](size_t bytes) -> void* {
    void* p = ws + off;
    off += (bytes + 255) & ~(size_t)255;
    return p;
  };

  _Float16* X16 = (_Float16*)alloc((size_t)T_STEPS * NB * 64 * 2);
  _Float16* WkT[2][3];
  for (int d = 0; d < 2; ++d)
    for (int l = 0; l < 3; ++l)
      WkT[d][l] = (_Float16*)alloc((size_t)NGATE * (l == 0 ? 320 : 512) * 2);
  _Float16* WpT[2][3];
  for (int d = 0; d < 2; ++d)
    for (int l = 0; l < 3; ++l)
      WpT[d][l] = (_Float16*)alloc((size_t)PROJ * HID * 2);
  _Float16* Hbuf = (_Float16*)alloc(6UL * 8 * SLOT * 2);    // 8-slot rings
  float* cst = (float*)alloc(6UL * NB * HID * 4);
  _Float16* gbuf = (_Float16*)alloc(6UL * NB * HID * 2);
  _Float16* embed = (_Float16*)alloc(4UL * SLOT * 2);
  int* cntG = (int*)alloc(162UL * 30 * 4);
  int* cntP = (int*)alloc(162UL * 30 * 4);

  // ---- prep ----
  {
    size_t tot = (size_t)T_STEPS * NB * 64;
    convX<<<dim3((unsigned)((tot + 255) / 256)), 256, 0, stream>>>(X, X16, tot);
  }
  for (int d = 0; d < 2; ++d)
    for (int l = 0; l < 3; ++l) {
      int Kpad = (l == 0) ? 320 : 512;
      size_t tot = (size_t)NGATE * Kpad;
      conv_wk<<<dim3((unsigned)((tot + 255) / 256)), 256, 0, stream>>>(
          Wk[d][l], WkT[d][l], (l == 0) ? 0 : 1, Kpad, tot);
      size_t totp = (size_t)PROJ * HID;
      conv_wp<<<dim3((unsigned)((totp + 255) / 256)), 256, 0, stream>>>(Wp[d][l], WpT[d][l], totp);
    }
  hipMemsetAsync(Hbuf, 0, 6UL * 8 * SLOT * 2, stream);
  hipMemsetAsync(cst, 0, 6UL * NB * HID * 4, stream);
  hipMemsetAsync(cntG, 0, 162UL * 30 * 4, stream);
  hipMemsetAsync(cntP, 0, 162UL * 30 * 4, stream);

  // ---- dataflow persistent kernel ----
  DFArgs dfa;
  dfa.X16 = X16;
  for (int d = 0; d < 2; ++d)
    for (int l = 0; l < 3; ++l) {
      int z = l * 2 + d;
      dfa.WkT[z] = WkT[d][l];
      dfa.bias[z] = Bi[d][l];
      dfa.WpT[z] = WpT[d][l];
    }
  dfa.Hbuf = Hbuf; dfa.cst = cst; dfa.gbuf = gbuf; dfa.embed = embed;
  dfa.cntG = cntG; dfa.cntP = cntP;

  void* kargs[] = { (void*)&dfa };
  hipError_t err = hipLaunchCooperativeKernel((void*)lstm_df, dim3(780), dim3(512), kargs, 0, stream);
  if (err != hipSuccess)
    lstm_df<<<dim3(780), 512, 0, stream>>>(dfa);   // fallback: plain launch (occupancy forced by launch_bounds)

  readout<<<dim3(NB), 256, 0, stream>>>(embed, (float*)d_out);
}